// Round 11
// baseline (313.703 us; speedup 1.0000x reference)
//
#include <hip/hip_runtime.h>
#include <math.h>

// x:(4,16,256,128)f32  w_qkv:(128,384)  w_out:(128,128)  b_out:(128)  y:(4,16,256,128)f32
// Reshape map: J=pos>>7, d/e=(pos&127)*32+(c>>2), a=c&3.  Per (b,a) pair:
// flash attn seq=4096 dim=32, Q=(10*log2e)*l2norm4(k), K=V=M(v), M[e][J]=v.
// r10 = r9 swapped-operand no-LDS attention + optional e-split x2 (flash
// split-K with merge kernel; gated on ws_size) + 1024-block kv kernel.
// ws: Qhi|Qlo [pair][d][J] bf16, Mhi|Mlo [pair][e][J] bf16, Mpv2 [pair][n][e'']
//     bf16, outb bf16 (24MB); + split extras: Opart f32 16MB, ml float2 1MB.
// (resubmission of round-10 kernel: GPU acquisition timed out, never benched)

#define SEQ 4096
#define PAIR_ELEMS (SEQ * 32)

typedef __attribute__((ext_vector_type(8))) short bf16x8;
typedef __attribute__((ext_vector_type(4))) float f32x4;

static __device__ __forceinline__ unsigned short f2bf(float x) {
    unsigned u = __float_as_uint(x);
    u += 0x7fffu + ((u >> 16) & 1u);
    return (unsigned short)(u >> 16);
}
static __device__ __forceinline__ float bf2f(unsigned short h) {
    return __uint_as_float(((unsigned)h) << 16);
}

// ---------------------------------------------------------------------------
// Kernel 1: k/v GEMM + in-thread l2norm + bf16 hi/lo split.
// r10: 1024 blocks (b, p7, half): half-split into separate blocks; thread
// owns 4 channels x 4 J-rows. Store layouts byte-identical to r9.
// ---------------------------------------------------------------------------
__global__ __launch_bounds__(256) void kv_kernel(const float* __restrict__ x,
                                                 const float* __restrict__ wqkv,
                                                 unsigned short* __restrict__ Qhi,
                                                 unsigned short* __restrict__ Qlo,
                                                 unsigned short* __restrict__ Mhi,
                                                 unsigned short* __restrict__ Mlo,
                                                 unsigned short* __restrict__ Mpv2) {
    __shared__ __align__(16) float xs[32][128];              // 16 KB
    __shared__ __align__(8) unsigned short vstage[32][128];  // 8 KB

    const int bid  = blockIdx.x;          // 1024
    const int b    = bid >> 8;
    const int p7   = (bid >> 1) & 127;
    const int half = bid & 1;             // 0: k, 1: v
    const int t    = threadIdx.x;
    const int q    = t & 31;              // channel group (cg) 0..31
    const int rg   = t >> 5;              // J-block: rows 4rg..4rg+3 (rg 0..7)
    const int woff = 128 + (half << 7) + (q << 2);

    // stage x rows (coalesced float4)
    {
        const float* xb = x + ((size_t)(b * SEQ + p7)) * 128;
#pragma unroll
        for (int uu = 0; uu < 4; ++uu) {
            int idx = t + (uu << 8);               // 0..1023
            int j   = idx >> 5;
            int c4  = idx & 31;
            *(float4*)&xs[j][c4 * 4] =
                *(const float4*)(xb + (size_t)j * (128 * 128) + c4 * 4);
        }
    }
    __syncthreads();

    float acc[4][4];
#pragma unroll
    for (int jr = 0; jr < 4; ++jr)
#pragma unroll
        for (int a = 0; a < 4; ++a) acc[jr][a] = 0.f;

    // depth-1 prefetch pipeline on the w-tiles
    float4 wA[4], wB[4];
#pragma unroll
    for (int i = 0; i < 4; ++i)
        wA[i] = *(const float4*)(wqkv + (size_t)i * 384 + woff);

    auto gstep = [&](float4 (&wcur)[4], float4 (&wnxt)[4], int i4) {
        const int i4n = (i4 + 4) & 127;            // wraps harmlessly on last
#pragma unroll
        for (int i = 0; i < 4; ++i)
            wnxt[i] = *(const float4*)(wqkv + (size_t)(i4n + i) * 384 + woff);
#pragma unroll
        for (int jr = 0; jr < 4; ++jr) {
            float4 xv = *(const float4*)&xs[4 * rg + jr][i4];
            acc[jr][0] = fmaf(xv.x, wcur[0].x, acc[jr][0]);
            acc[jr][1] = fmaf(xv.x, wcur[0].y, acc[jr][1]);
            acc[jr][2] = fmaf(xv.x, wcur[0].z, acc[jr][2]);
            acc[jr][3] = fmaf(xv.x, wcur[0].w, acc[jr][3]);
            acc[jr][0] = fmaf(xv.y, wcur[1].x, acc[jr][0]);
            acc[jr][1] = fmaf(xv.y, wcur[1].y, acc[jr][1]);
            acc[jr][2] = fmaf(xv.y, wcur[1].z, acc[jr][2]);
            acc[jr][3] = fmaf(xv.y, wcur[1].w, acc[jr][3]);
            acc[jr][0] = fmaf(xv.z, wcur[2].x, acc[jr][0]);
            acc[jr][1] = fmaf(xv.z, wcur[2].y, acc[jr][1]);
            acc[jr][2] = fmaf(xv.z, wcur[2].z, acc[jr][2]);
            acc[jr][3] = fmaf(xv.z, wcur[2].w, acc[jr][3]);
            acc[jr][0] = fmaf(xv.w, wcur[3].x, acc[jr][0]);
            acc[jr][1] = fmaf(xv.w, wcur[3].y, acc[jr][1]);
            acc[jr][2] = fmaf(xv.w, wcur[3].z, acc[jr][2]);
            acc[jr][3] = fmaf(xv.w, wcur[3].w, acc[jr][3]);
        }
    };
    for (int i4 = 0; i4 < 128; i4 += 8) {
        gstep(wA, wB, i4);
        gstep(wB, wA, i4 + 4);
    }

    const int pairbase = b << 2;
    const int de = (p7 << 5) + q;

    if (half == 0) {
        float qn[4][4];
#pragma unroll
        for (int jr = 0; jr < 4; ++jr) {
            float s = acc[jr][0] * acc[jr][0] + acc[jr][1] * acc[jr][1]
                    + acc[jr][2] * acc[jr][2] + acc[jr][3] * acc[jr][3];
            float inv = 14.426950408889634f / fmaxf(sqrtf(s), 1e-12f);
#pragma unroll
            for (int a = 0; a < 4; ++a) qn[jr][a] = acc[jr][a] * inv;
        }
#pragma unroll
        for (int a = 0; a < 4; ++a) {
            unsigned h01 = (unsigned)f2bf(qn[0][a]) | ((unsigned)f2bf(qn[1][a]) << 16);
            unsigned h23 = (unsigned)f2bf(qn[2][a]) | ((unsigned)f2bf(qn[3][a]) << 16);
            unsigned l01 = (unsigned)f2bf(qn[0][a] - bf2f(f2bf(qn[0][a])))
                         | ((unsigned)f2bf(qn[1][a] - bf2f(f2bf(qn[1][a]))) << 16);
            unsigned l23 = (unsigned)f2bf(qn[2][a] - bf2f(f2bf(qn[2][a])))
                         | ((unsigned)f2bf(qn[3][a] - bf2f(f2bf(qn[3][a]))) << 16);
            size_t off = (size_t)(pairbase + a) * PAIR_ELEMS + (size_t)de * 32 + 4 * rg;
            *(uint2*)(Qhi + off) = make_uint2(h01, h23);
            *(uint2*)(Qlo + off) = make_uint2(l01, l23);
        }
    } else {
#pragma unroll
        for (int a = 0; a < 4; ++a) {
            unsigned h01 = (unsigned)f2bf(acc[0][a]) | ((unsigned)f2bf(acc[1][a]) << 16);
            unsigned h23 = (unsigned)f2bf(acc[2][a]) | ((unsigned)f2bf(acc[3][a]) << 16);
            unsigned l01 = (unsigned)f2bf(acc[0][a] - bf2f(f2bf(acc[0][a])))
                         | ((unsigned)f2bf(acc[1][a] - bf2f(f2bf(acc[1][a]))) << 16);
            unsigned l23 = (unsigned)f2bf(acc[2][a] - bf2f(f2bf(acc[2][a])))
                         | ((unsigned)f2bf(acc[3][a] - bf2f(f2bf(acc[3][a]))) << 16);
            size_t off = (size_t)(pairbase + a) * PAIR_ELEMS + (size_t)de * 32 + 4 * rg;
            *(uint2*)(Mhi + off) = make_uint2(h01, h23);
            *(uint2*)(Mlo + off) = make_uint2(l01, l23);
        }
#pragma unroll
        for (int jr = 0; jr < 4; ++jr) {
            unsigned short h0 = f2bf(acc[jr][0]);
            unsigned short h1 = f2bf(acc[jr][1]);
            unsigned short h2 = f2bf(acc[jr][2]);
            unsigned short h3 = f2bf(acc[jr][3]);
            *(uint2*)&vstage[4 * rg + jr][4 * q] =
                make_uint2((unsigned)h0 | ((unsigned)h1 << 16),
                           (unsigned)h2 | ((unsigned)h3 << 16));
        }
    }
    __syncthreads();

    if (half == 1) {
        // Mpv2[pair][n=J][e''] scatter — verbatim from r9 passing kernel.
        unsigned* mpv32 = (unsigned*)Mpv2;
#pragma unroll
        for (int uu = 0; uu < 8; ++uu) {
            int task = t + (uu << 8);              // 2048 tasks
            int w  = task & 15;
            int jj = (task >> 4) & 31;
            int aa = task >> 9;
            unsigned lo = vstage[jj][(w << 3) + aa];        // cg = 2w
            unsigned hi = vstage[jj][(w << 3) + 4 + aa];    // cg = 2w+1
            int pr = (b << 2) + aa;
            size_t dst = (size_t)pr * 65536 + (size_t)jj * 2048
                       + ((size_t)(p7 >> 1)) * 32
                       + (size_t)((p7 & 1) * 16)
                       + (size_t)(((w >> 1) & 3) * 4)
                       + (size_t)((w >> 3) * 2)
                       + (size_t)(w & 1);
            mpv32[dst] = lo | (hi << 16);
        }
    }
}

// ---------------------------------------------------------------------------
// Kernel 2: swapped-operand MFMA flash attention (r9 body). Grid 512 = full-e
// per block (writes outb); grid 1024 = e-split x2 (writes Opart f32 + ml).
// ---------------------------------------------------------------------------
__global__ __launch_bounds__(256, 2) void attn_kernel(const unsigned short* __restrict__ Qhi,
                                                      const unsigned short* __restrict__ Qlo,
                                                      const unsigned short* __restrict__ Mhi,
                                                      const unsigned short* __restrict__ Mlo,
                                                      const unsigned short* __restrict__ Mpv2,
                                                      unsigned short* __restrict__ outb,
                                                      float* __restrict__ Opart,
                                                      float* __restrict__ ml) {
    const int bid   = blockIdx.x;
    const bool split = (gridDim.x != 512);
    int pair, dblk, eh;
    if (!split) {
        pair = ((bid & 7) << 1) + (bid >> 8);
        dblk = (bid & 255) >> 3;
        eh   = 0;
    } else {
        pair = ((bid & 7) << 1) | ((bid >> 3) & 1);
        dblk = (bid >> 4) & 31;
        eh   = bid >> 9;
    }
    const int CH    = split ? (SEQ / 2) : SEQ;
    const int emask = CH - 1;
    const int ebase = eh * CH;

    const int t    = threadIdx.x;
    const int wid  = t >> 6;
    const int lane = t & 63;
    const int col  = lane & 15;
    const int g    = lane >> 4;
    const int d0   = dblk * 128 + wid * 32;

    const size_t pb = (size_t)pair * PAIR_ELEMS;

    bf16x8 ah[2], al[2];
#pragma unroll
    for (int s = 0; s < 2; ++s) {
        size_t o = pb + (size_t)(d0 + 16 * s + col) * 32 + g * 8;
        ah[s] = *(const bf16x8*)(Qhi + o);
        al[s] = *(const bf16x8*)(Qlo + o);
    }

    const unsigned short* mh = Mhi + pb;
    const unsigned short* ml_ = Mlo + pb;
    const unsigned short* mp = Mpv2 + pb;        // [n:32][e'':4096]
    const f32x4 z = {0.f, 0.f, 0.f, 0.f};

    // ---- phase 1: exact per-d max of bf16 QK over this block's e-chunk
    float rmax[2] = {-3e38f, -3e38f};
    {
        bf16x8 pA[4], pB[4];
#pragma unroll
        for (int cc = 0; cc < 4; ++cc)
            pA[cc] = *(const bf16x8*)(mh + (size_t)(ebase + 16 * cc + col) * 32 + g * 8);

        auto sweep = [&](bf16x8 (&cur)[4], bf16x8 (&nxt)[4], int e0) {
            const int en = ebase + ((e0 - ebase + 64) & emask);
#pragma unroll
            for (int cc = 0; cc < 4; ++cc)
                nxt[cc] = *(const bf16x8*)(mh + (size_t)(en + 16 * cc + col) * 32 + g * 8);
#pragma unroll
            for (int cc = 0; cc < 4; ++cc) {
#pragma unroll
                for (int s = 0; s < 2; ++s) {
                    f32x4 sv = __builtin_amdgcn_mfma_f32_16x16x32_bf16(cur[cc], ah[s], z, 0, 0, 0);
                    rmax[s] = fmaxf(rmax[s], fmaxf(fmaxf(sv[0], sv[1]), fmaxf(sv[2], sv[3])));
                }
            }
        };
        for (int eo = 0; eo < CH; eo += 128) {
            sweep(pA, pB, ebase + eo);
            sweep(pB, pA, ebase + eo + 64);
        }
    }
#pragma unroll
    for (int s = 0; s < 2; ++s) {
        float m = rmax[s];
        m = fmaxf(m, __shfl_xor(m, 16));
        m = fmaxf(m, __shfl_xor(m, 32));
        rmax[s] = m;
    }
    f32x4 minit[2];
#pragma unroll
    for (int s = 0; s < 2; ++s)
        minit[s] = (f32x4){-rmax[s], -rmax[s], -rmax[s], -rmax[s]};

    f32x4 O[2][2];   // [s][nh]: O[d=d0+16s+col][n=16nh+4g+r]
    float lsum[2] = {0.f, 0.f};
#pragma unroll
    for (int s = 0; s < 2; ++s)
#pragma unroll
        for (int nh = 0; nh < 2; ++nh) O[s][nh] = (f32x4){0.f, 0.f, 0.f, 0.f};

    // ---- phase 2: main flash loop (r9 body)
    {
        bf16x8 tA[12], tB[12];
#pragma unroll
        for (int cc = 0; cc < 4; ++cc) {
            size_t ro = (size_t)(ebase + 16 * cc + col) * 32 + g * 8;
            tA[cc]     = *(const bf16x8*)(mh + ro);
            tA[4 + cc] = *(const bf16x8*)(ml_ + ro);
        }
#pragma unroll
        for (int nh = 0; nh < 2; ++nh)
#pragma unroll
            for (int m = 0; m < 2; ++m)
                tA[8 + 2 * nh + m] =
                    *(const bf16x8*)(mp + (size_t)(16 * nh + col) * SEQ + ebase + 32 * m + 8 * g);

        auto flash = [&](bf16x8 (&cur)[12], bf16x8 (&nxt)[12], int e0) {
            const int en = ebase + ((e0 - ebase + 64) & emask);
            // prefetch next tile (issued before any use of cur)
#pragma unroll
            for (int cc = 0; cc < 4; ++cc) {
                size_t ro = (size_t)(en + 16 * cc + col) * 32 + g * 8;
                nxt[cc]     = *(const bf16x8*)(mh + ro);
                nxt[4 + cc] = *(const bf16x8*)(ml_ + ro);
            }
#pragma unroll
            for (int nh = 0; nh < 2; ++nh)
#pragma unroll
                for (int m = 0; m < 2; ++m)
                    nxt[8 + 2 * nh + m] =
                        *(const bf16x8*)(mp + (size_t)(16 * nh + col) * SEQ
                                         + en + 32 * m + 8 * g);

            // S^T = M * Q^T (hi/lo split, C-init = -max)
            f32x4 S[2][4];
#pragma unroll
            for (int cc = 0; cc < 4; ++cc) {
#pragma unroll
                for (int s = 0; s < 2; ++s) {
                    f32x4 tac = __builtin_amdgcn_mfma_f32_16x16x32_bf16(cur[4 + cc], ah[s], minit[s], 0, 0, 0);
                    tac = __builtin_amdgcn_mfma_f32_16x16x32_bf16(cur[cc], al[s], tac, 0, 0, 0);
                    S[s][cc] = __builtin_amdgcn_mfma_f32_16x16x32_bf16(cur[cc], ah[s], tac, 0, 0, 0);
                }
            }
            // P = exp2(S) -> bf16 u32 pairs (per-lane)
            unsigned pw[2][4][2];
#pragma unroll
            for (int s = 0; s < 2; ++s) {
#pragma unroll
                for (int cc = 0; cc < 4; ++cc) {
                    float p0 = __builtin_amdgcn_exp2f(S[s][cc][0]);
                    float p1 = __builtin_amdgcn_exp2f(S[s][cc][1]);
                    float p2 = __builtin_amdgcn_exp2f(S[s][cc][2]);
                    float p3 = __builtin_amdgcn_exp2f(S[s][cc][3]);
                    lsum[s] += (p0 + p1) + (p2 + p3);
                    asm("v_cvt_pk_bf16_f32 %0, %1, %2" : "=v"(pw[s][cc][0]) : "v"(p0), "v"(p1));
                    asm("v_cvt_pk_bf16_f32 %0, %1, %2" : "=v"(pw[s][cc][1]) : "v"(p2), "v"(p3));
                }
            }
            // O^T += M^T * P via 16x16x32 MFMAs
#pragma unroll
            for (int s = 0; s < 2; ++s) {
#pragma unroll
                for (int m = 0; m < 2; ++m) {
                    unsigned pk4[4] = {pw[s][2 * m][0], pw[s][2 * m][1],
                                       pw[s][2 * m + 1][0], pw[s][2 * m + 1][1]};
                    bf16x8 pbf = *(bf16x8*)pk4;
                    O[s][0] = __builtin_amdgcn_mfma_f32_16x16x32_bf16(cur[8 + 0 + m], pbf, O[s][0], 0, 0, 0);
                    O[s][1] = __builtin_amdgcn_mfma_f32_16x16x32_bf16(cur[8 + 2 + m], pbf, O[s][1], 0, 0, 0);
                }
            }
        };
        for (int eo = 0; eo < CH; eo += 128) {
            flash(tA, tB, ebase + eo);
            flash(tB, tA, ebase + eo + 64);
        }
    }

    // ---- final l reduce (lanes sharing col)
#pragma unroll
    for (int s = 0; s < 2; ++s) {
        float l = lsum[s];
        l += __shfl_xor(l, 16);
        l += __shfl_xor(l, 32);
        lsum[s] = l;
    }

    if (!split) {
        // epilogue: outb[b][d][n*4+a], d = d0+16s+col, n = 16nh+4g+r
        const int bb = pair >> 2;
        const int aa = pair & 3;
#pragma unroll
        for (int s = 0; s < 2; ++s) {
            float inv = 1.0f / lsum[s];
            size_t rowb = ((size_t)(bb * SEQ + d0 + 16 * s + col)) * 128;
#pragma unroll
            for (int nh = 0; nh < 2; ++nh) {
#pragma unroll
                for (int r = 0; r < 4; ++r) {
                    int n = 16 * nh + 4 * g + r;
                    outb[rowb + n * 4 + aa] = f2bf(O[s][nh][r] * inv);
                }
            }
        }
    } else {
        // partials: Opart[(((pair*2+eh)*32+dblk)*4+wid)*64+lane][16] f32,
        // ml[((((pair*2+eh)*32+dblk)*4+wid)*2+s)*16+col] = {m, l}
        size_t slot = ((((size_t)(pair * 2 + eh) * 32 + dblk) * 4 + wid) * 64 + lane) * 16;
#pragma unroll
        for (int s = 0; s < 2; ++s)
#pragma unroll
            for (int nh = 0; nh < 2; ++nh)
                *(f32x4*)(Opart + slot + s * 8 + nh * 4) = O[s][nh];
        if (g == 0) {
            float2* mlv = (float2*)ml;
#pragma unroll
            for (int s = 0; s < 2; ++s) {
                size_t mi = ((((size_t)(pair * 2 + eh) * 32 + dblk) * 4 + wid) * 2 + s) * 16 + col;
                mlv[mi] = make_float2(rmax[s], lsum[s]);
            }
        }
    }
}

// ---------------------------------------------------------------------------
// Kernel 2b: split-K merge — combine the two e-chunk partials, write outb.
// 512 blocks x 256 threads; thread = one attn lane-slot.
// ---------------------------------------------------------------------------
__global__ __launch_bounds__(256) void merge_kernel(const float* __restrict__ Opart,
                                                    const float* __restrict__ ml,
                                                    unsigned short* __restrict__ outb) {
    const int gid  = blockIdx.x * 256 + threadIdx.x;   // 131072
    const int lane = gid & 63;
    const int wid  = (gid >> 6) & 3;
    const int dblk = (gid >> 8) & 31;
    const int pair = gid >> 13;
    const int col  = lane & 15;
    const int g    = lane >> 4;
    const int d0   = dblk * 128 + wid * 32;
    const int bb   = pair >> 2;
    const int aa   = pair & 3;

    const size_t slot0 = ((((size_t)(pair * 2 + 0) * 32 + dblk) * 4 + wid) * 64 + lane) * 16;
    const size_t slot1 = ((((size_t)(pair * 2 + 1) * 32 + dblk) * 4 + wid) * 64 + lane) * 16;
    const float2* mlv = (const float2*)ml;

#pragma unroll
    for (int s = 0; s < 2; ++s) {
        size_t mi0 = ((((size_t)(pair * 2 + 0) * 32 + dblk) * 4 + wid) * 2 + s) * 16 + col;
        size_t mi1 = ((((size_t)(pair * 2 + 1) * 32 + dblk) * 4 + wid) * 2 + s) * 16 + col;
        float2 a = mlv[mi0];
        float2 c = mlv[mi1];
        float m  = fmaxf(a.x, c.x);
        float w0 = __builtin_amdgcn_exp2f(a.x - m);
        float w1 = __builtin_amdgcn_exp2f(c.x - m);
        float inv = 1.0f / (a.y * w0 + c.y * w1);
        size_t rowb = ((size_t)(bb * SEQ + d0 + 16 * s + col)) * 128;
#pragma unroll
        for (int nh = 0; nh < 2; ++nh) {
            f32x4 o0 = *(const f32x4*)(Opart + slot0 + s * 8 + nh * 4);
            f32x4 o1 = *(const f32x4*)(Opart + slot1 + s * 8 + nh * 4);
#pragma unroll
            for (int r = 0; r < 4; ++r) {
                int n = 16 * nh + 4 * g + r;
                outb[rowb + n * 4 + aa] = f2bf((o0[r] * w0 + o1[r] * w1) * inv);
            }
        }
    }
}

// ---------------------------------------------------------------------------
// Kernel 3: y = opre(bf16) @ w_out + b_out  (fp32 vector GEMM) — unchanged
// ---------------------------------------------------------------------------
__global__ __launch_bounds__(256) void out_kernel(const unsigned short* __restrict__ opre,
                                                  const float* __restrict__ wout,
                                                  const float* __restrict__ bout,
                                                  float* __restrict__ y) {
    __shared__ __align__(16) float xs[8][128];
    const int r0 = blockIdx.x * 8;
    const int t  = threadIdx.x;
    {
        const unsigned* src = (const unsigned*)(opre + (size_t)r0 * 128);
        unsigned v0 = src[t * 2], v1 = src[t * 2 + 1];
        float* dst = &xs[0][0] + t * 4;
        dst[0] = bf2f((unsigned short)(v0 & 0xffff));
        dst[1] = bf2f((unsigned short)(v0 >> 16));
        dst[2] = bf2f((unsigned short)(v1 & 0xffff));
        dst[3] = bf2f((unsigned short)(v1 >> 16));
    }
    __syncthreads();

    const int c  = t & 127;
    const int rh = (t >> 7) * 4;
    float acc[4] = {0.f, 0.f, 0.f, 0.f};

    for (int i = 0; i < 128; i += 4) {
        float w0 = wout[(i + 0) * 128 + c];
        float w1 = wout[(i + 1) * 128 + c];
        float w2 = wout[(i + 2) * 128 + c];
        float w3 = wout[(i + 3) * 128 + c];
#pragma unroll
        for (int p = 0; p < 4; ++p) {
            float4 xp = *(const float4*)&xs[rh + p][i];
            acc[p] = fmaf(xp.x, w0, acc[p]);
            acc[p] = fmaf(xp.y, w1, acc[p]);
            acc[p] = fmaf(xp.z, w2, acc[p]);
            acc[p] = fmaf(xp.w, w3, acc[p]);
        }
    }
    float bb = bout[c];
#pragma unroll
    for (int p = 0; p < 4; ++p) {
        y[((size_t)(r0 + rh + p)) * 128 + c] = acc[p] + bb;
    }
}

// ---------------------------------------------------------------------------
extern "C" void kernel_launch(void* const* d_in, const int* in_sizes, int n_in,
                              void* d_out, int out_size, void* d_ws, size_t ws_size,
                              hipStream_t stream) {
    const float* x    = (const float*)d_in[0];
    const float* wqkv = (const float*)d_in[1];
    const float* wout = (const float*)d_in[2];
    const float* bout = (const float*)d_in[3];
    float* y = (float*)d_out;

    unsigned short* Qhi  = (unsigned short*)d_ws;
    unsigned short* Qlo  = Qhi + (size_t)16 * PAIR_ELEMS;
    unsigned short* Mhi  = Qlo + (size_t)16 * PAIR_ELEMS;
    unsigned short* Mlo  = Mhi + (size_t)16 * PAIR_ELEMS;
    unsigned short* Mpv2 = Mlo + (size_t)16 * PAIR_ELEMS;
    unsigned short* outb = Mpv2 + (size_t)16 * PAIR_ELEMS;
    float* Opart = (float*)(outb + (size_t)16 * PAIR_ELEMS);   // 16 MB
    float* ml    = Opart + (size_t)4194304;                    // 1 MB

    // base 24 MB + Opart 16 MB + ml 1 MB = 41 MB
    const bool split = ws_size >= (size_t)41 * 1024 * 1024;

    kv_kernel<<<1024, 256, 0, stream>>>(x, wqkv, Qhi, Qlo, Mhi, Mlo, Mpv2);
    if (split) {
        attn_kernel<<<1024, 256, 0, stream>>>(Qhi, Qlo, Mhi, Mlo, Mpv2, outb, Opart, ml);
        merge_kernel<<<512, 256, 0, stream>>>(Opart, ml, outb);
    } else {
        attn_kernel<<<512, 256, 0, stream>>>(Qhi, Qlo, Mhi, Mlo, Mpv2, outb, Opart, ml);
    }
    out_kernel<<<2048, 256, 0, stream>>>(outb, wout, bout, y);
}